// Round 4
// baseline (3191.932 us; speedup 1.0000x reference)
//
#include <hip/hip_runtime.h>
#include <hip/hip_fp16.h>

// Problem constants
#define BB 64
#define TT 2048
#define II 128
#define HH 128
#define NG 512  // 4*H

typedef _Float16 h2_t __attribute__((ext_vector_type(2)));

#if defined(__has_builtin)
#if __has_builtin(__builtin_amdgcn_fdot2)
#define HAVE_FDOT2 1
#endif
#endif

__device__ __forceinline__ float fdot2f(h2_t a, h2_t b, float c) {
#ifdef HAVE_FDOT2
  return __builtin_amdgcn_fdot2(a, b, c, false);
#else
  float d;
  asm("v_dot2_f32_f16 %0, %1, %2, %3" : "=v"(d) : "v"(a), "v"(b), "v"(c));
  return d;
#endif
}

__device__ __forceinline__ float fast_sigmoid(float x) {
  float t = __builtin_amdgcn_exp2f(-1.4426950408889634f * x);
  return __builtin_amdgcn_rcpf(1.0f + t);
}

// sigmoid(x) normally; tanh(x) = 2*sigmoid(2x)-1 for the g-gate rows.
__device__ __forceinline__ float act_gate(float x, bool tanh_sel) {
  float xx = tanh_sel ? 2.0f * x : x;
  float s = fast_sigmoid(xx);
  return tanh_sel ? 2.0f * s - 1.0f : s;
}

__device__ __forceinline__ float fast_tanh(float x) {
  return 2.0f * fast_sigmoid(2.0f * x) - 1.0f;
}

// LDS-only barrier: does NOT drain vmcnt, so global prefetch/stores stay queued.
__device__ __forceinline__ void bar_lds() {
  asm volatile("s_waitcnt lgkmcnt(0)\n\ts_barrier" ::: "memory");
}

union F4H {
  float4 f4;
  h2_t h[4];
};

// ---------------------------------------------------------------------------
// Transpose Wx0 [512][128] -> WT [128][512] (fp32), tiny
// ---------------------------------------------------------------------------
__global__ void wx0_transpose(const float* __restrict__ W, float* __restrict__ WT) {
  int idx = blockIdx.x * 256 + threadIdx.x;
  if (idx < NG * II) {
    int n = idx >> 7;
    int k = idx & 127;
    WT[k * NG + n] = W[idx];
  }
}

// ---------------------------------------------------------------------------
// Xg = x @ Wx0^T + b0, stored f16 TRANSPOSED as [B][512][T] so the
// recurrence reads each gate stream contiguously along t.
// ---------------------------------------------------------------------------
__global__ __launch_bounds__(256) void xg0_gemm(const float* __restrict__ X,
                                                const float* __restrict__ WT,  // [128][512]
                                                const float* __restrict__ bias,
                                                __half* __restrict__ Xg) {   // [B][512][T]
  __shared__ float As[64][132];
  __shared__ float Bs[128][64];
  const int m0 = blockIdx.x * 64;
  const int n0 = blockIdx.y * 64;
  const int tid = threadIdx.x;

  {
    const float4* xv = (const float4*)(X + (size_t)m0 * II);
#pragma unroll
    for (int r = 0; r < 8; ++r) {
      int f = tid + 256 * r;
      int m = f >> 5;
      int c4 = f & 31;
      float4 v = xv[m * 32 + c4];
      *(float4*)&As[m][c4 * 4] = v;
    }
  }
  {
#pragma unroll
    for (int r = 0; r < 8; ++r) {
      int f = tid + 256 * r;
      int k = f >> 4;
      int q = f & 15;
      float4 v = *(const float4*)(WT + (size_t)k * NG + n0 + q * 4);
      *(float4*)&Bs[k][q * 4] = v;
    }
  }
  __syncthreads();

  const int tx = tid & 15;
  const int ty = tid >> 4;
  float acc[4][4];
#pragma unroll
  for (int i = 0; i < 4; ++i)
#pragma unroll
    for (int j = 0; j < 4; ++j) acc[i][j] = 0.0f;

#pragma unroll 4
  for (int k = 0; k < 128; ++k) {
    float a0 = As[ty * 4 + 0][k];
    float a1 = As[ty * 4 + 1][k];
    float a2 = As[ty * 4 + 2][k];
    float a3 = As[ty * 4 + 3][k];
    float4 bv = *(const float4*)&Bs[k][tx * 4];
    acc[0][0] = fmaf(a0, bv.x, acc[0][0]);
    acc[0][1] = fmaf(a0, bv.y, acc[0][1]);
    acc[0][2] = fmaf(a0, bv.z, acc[0][2]);
    acc[0][3] = fmaf(a0, bv.w, acc[0][3]);
    acc[1][0] = fmaf(a1, bv.x, acc[1][0]);
    acc[1][1] = fmaf(a1, bv.y, acc[1][1]);
    acc[1][2] = fmaf(a1, bv.z, acc[1][2]);
    acc[1][3] = fmaf(a1, bv.w, acc[1][3]);
    acc[2][0] = fmaf(a2, bv.x, acc[2][0]);
    acc[2][1] = fmaf(a2, bv.y, acc[2][1]);
    acc[2][2] = fmaf(a2, bv.z, acc[2][2]);
    acc[2][3] = fmaf(a2, bv.w, acc[2][3]);
    acc[3][0] = fmaf(a3, bv.x, acc[3][0]);
    acc[3][1] = fmaf(a3, bv.y, acc[3][1]);
    acc[3][2] = fmaf(a3, bv.z, acc[3][2]);
    acc[3][3] = fmaf(a3, bv.w, acc[3][3]);
  }

  float4 bvec = *(const float4*)(bias + n0 + tx * 4);
  float bb[4] = {bvec.x, bvec.y, bvec.z, bvec.w};
  const int b = m0 >> 11;        // 2048 % 64 == 0, tile never straddles b
  const int t0 = m0 & 2047;
  __half* base = Xg + (size_t)b * NG * TT + (size_t)t0 + (size_t)(ty * 4);
#pragma unroll
  for (int j = 0; j < 4; ++j) {
    int nn = n0 + tx * 4 + j;
    union { __half2 h[2]; uint2 u; } pk;
    pk.h[0] = __halves2half2(__float2half(acc[0][j] + bb[j]),
                             __float2half(acc[1][j] + bb[j]));
    pk.h[1] = __halves2half2(__float2half(acc[2][j] + bb[j]),
                             __float2half(acc[3][j] + bb[j]));
    *(uint2*)(base + (size_t)nn * TT) = pk.u;
  }
}

// ---------------------------------------------------------------------------
// Recurrence: one WG per batch element, 1024 threads. Thread n = 2r+p owns
// K-half p of gate row r (96 f16x2 weight regs). amdgpu_waves_per_eu(4,4)
// pins occupancy at exactly 4 waves/EU (the launch's real occupancy: 64 WGs
// = 1 block/CU), giving the allocator the full 128-VGPR budget so weights
// stay in arch VGPRs (NO v_accvgpr shuffling -> ~2x less VALU issue).
// Layer-skewed pipeline: iteration i computes g0(i) AND g1(i-1) in ONE dot
// phase (2 barriers/step). Pair partials combined via shfl_xor(1).
// ---------------------------------------------------------------------------
__global__
__attribute__((amdgpu_flat_work_group_size(1024, 1024)))
__attribute__((amdgpu_waves_per_eu(4, 4)))
void lstm_rec(
    const __half* __restrict__ Xg,    // [B][512][T], includes b0
    const float* __restrict__ Wh0,    // [512][128]
    const float* __restrict__ Wx1,    // [512][128]
    const float* __restrict__ Wh1,    // [512][128]
    const float* __restrict__ b1,     // [512]
    float* __restrict__ out)          // output | hT | cT
{
  const int b = blockIdx.x;
  const int n = threadIdx.x;
  const int r = n >> 1;
  const int p = n & 1;
  const bool tanh_sel = ((r >> 7) == 2);

  // Per-thread K-half weight rows, f32 -> f16x2 registers (32 each)
  h2_t wh0[32], wx1[32], wh1[32];
  {
    const float2* p0 = (const float2*)(Wh0 + (size_t)r * HH + p * 64);
    const float2* p1 = (const float2*)(Wx1 + (size_t)r * HH + p * 64);
    const float2* p2 = (const float2*)(Wh1 + (size_t)r * HH + p * 64);
#pragma unroll
    for (int q = 0; q < 32; ++q) {
      float2 v0 = p0[q];
      float2 v1 = p1[q];
      float2 v2 = p2[q];
      wh0[q][0] = (_Float16)v0.x; wh0[q][1] = (_Float16)v0.y;
      wx1[q][0] = (_Float16)v1.x; wx1[q][1] = (_Float16)v1.y;
      wh1[q][0] = (_Float16)v2.x; wh1[q][1] = (_Float16)v2.y;
    }
  }
  const float bias1 = b1[r];

  __shared__ __align__(16) h2_t h0p[64];   // h0(t-1) as f16
  __shared__ __align__(16) h2_t h1p[64];   // h1(t-2) as f16
  __shared__ float gbuf[1024];             // [0..511]=g0 act, [512..1023]=g1 act

  if (n < 64) {
    h2_t z;
    z[0] = (_Float16)0.0f;
    z[1] = (_Float16)0.0f;
    h0p[n] = z;
    h1p[n] = z;
  }
  float c0 = 0.0f, c1 = 0.0f;
  float h0v = 0.0f, h1v = 0.0f;
  __syncthreads();

  const uint4* xs = (const uint4*)(Xg + ((size_t)b * NG + r) * TT);
  float* outp = out + (size_t)b * TT * HH;
  float* hT = out + (size_t)BB * TT * HH;   // [2][64][128]
  float* cT = hT + 2 * BB * HH;

  const float4* H0 = (const float4*)((const char*)h0p + (p << 7));
  const float4* H1 = (const float4*)((const char*)h1p + (p << 7));
  float* gdst = &gbuf[p * 512 + r];

  uint4 xcur = xs[0];

  for (int tc = 0; tc < TT / 8; ++tc) {
    uint4 xnext = xs[(tc + 1) & (TT / 8 - 1)];  // stays in flight across barriers
#pragma unroll
    for (int s = 0; s < 8; ++s) {
      const int i = tc * 8 + s;
      const float xg = (float)((const _Float16*)&xcur)[s];

      // ---- Phase 1: 96 dot2 -> partial g0(i) and g1(i-1) ----
      float a0 = 0.f, a1 = 0.f, x0 = 0.f, x1 = 0.f, w0 = 0.f, w1 = 0.f;
#pragma unroll
      for (int q = 0; q < 8; ++q) {
        F4H u0; u0.f4 = H0[q];
        F4H u1; u1.f4 = H1[q];
        a0 = fdot2f(wh0[4 * q + 0], u0.h[0], a0);
        a1 = fdot2f(wh0[4 * q + 1], u0.h[1], a1);
        a0 = fdot2f(wh0[4 * q + 2], u0.h[2], a0);
        a1 = fdot2f(wh0[4 * q + 3], u0.h[3], a1);
        x0 = fdot2f(wx1[4 * q + 0], u0.h[0], x0);
        x1 = fdot2f(wx1[4 * q + 1], u0.h[1], x1);
        x0 = fdot2f(wx1[4 * q + 2], u0.h[2], x0);
        x1 = fdot2f(wx1[4 * q + 3], u0.h[3], x1);
        w0 = fdot2f(wh1[4 * q + 0], u1.h[0], w0);
        w1 = fdot2f(wh1[4 * q + 1], u1.h[1], w1);
        w0 = fdot2f(wh1[4 * q + 2], u1.h[2], w0);
        w1 = fdot2f(wh1[4 * q + 3], u1.h[3], w1);
      }
      float acc0 = a0 + a1;                // partial Wh0.h0
      float acc1 = (x0 + x1) + (w0 + w1);  // partial Wx1.h0 + Wh1.h1
      acc0 += __shfl_xor(acc0, 1);
      acc1 += __shfl_xor(acc1, 1);
      // branch-free: even lane -> g0 row (add xg), odd lane -> g1 row (add b1)
      float val = p ? (acc1 + bias1) : (acc0 + xg);
      *gdst = act_gate(val, tanh_sel);
      bar_lds();

      // ---- Phase 2: cell updates (waves 0-1: L0 step i; waves 2-3: L1 step i-1)
      if (n < 128) {
        float gi = gbuf[n], gf = gbuf[n + 128], gg = gbuf[n + 256], go = gbuf[n + 384];
        c0 = gf * c0 + gi * gg;
        h0v = go * fast_tanh(c0);
        ((_Float16*)h0p)[n] = (_Float16)h0v;
      } else if (n < 256) {
        if (i > 0) {
          int jj = n - 128;
          float gi = gbuf[jj + 512], gf = gbuf[jj + 640], gg = gbuf[jj + 768], go = gbuf[jj + 896];
          c1 = gf * c1 + gi * gg;
          h1v = go * fast_tanh(c1);
          ((_Float16*)h1p)[jj] = (_Float16)h1v;
          outp[(size_t)(i - 1) * HH + jj] = h1v;
        }
      }
      bar_lds();
    }
    xcur = xnext;
  }

  // ---- Epilogue: g1 for step TT-1 (needs h0(TT-1), h1(TT-2)) ----
  {
    float x0 = 0.f, x1 = 0.f, w0 = 0.f, w1 = 0.f;
#pragma unroll
    for (int q = 0; q < 8; ++q) {
      F4H u0; u0.f4 = H0[q];
      F4H u1; u1.f4 = H1[q];
      x0 = fdot2f(wx1[4 * q + 0], u0.h[0], x0);
      x1 = fdot2f(wx1[4 * q + 1], u0.h[1], x1);
      x0 = fdot2f(wx1[4 * q + 2], u0.h[2], x0);
      x1 = fdot2f(wx1[4 * q + 3], u0.h[3], x1);
      w0 = fdot2f(wh1[4 * q + 0], u1.h[0], w0);
      w1 = fdot2f(wh1[4 * q + 1], u1.h[1], w1);
      w0 = fdot2f(wh1[4 * q + 2], u1.h[2], w0);
      w1 = fdot2f(wh1[4 * q + 3], u1.h[3], w1);
    }
    float acc1 = (x0 + x1) + (w0 + w1);
    acc1 += __shfl_xor(acc1, 1);
    if (p) *gdst = act_gate(acc1 + bias1, tanh_sel);
    bar_lds();
    if (n >= 128 && n < 256) {
      int jj = n - 128;
      float gi = gbuf[jj + 512], gf = gbuf[jj + 640], gg = gbuf[jj + 768], go = gbuf[jj + 896];
      c1 = gf * c1 + gi * gg;
      h1v = go * fast_tanh(c1);
      outp[(size_t)(TT - 1) * HH + jj] = h1v;
    }
  }

  // ---- Final states ----
  if (n < 128) {
    hT[b * HH + n] = h0v;
    cT[b * HH + n] = c0;
  } else if (n < 256) {
    int jj = n - 128;
    hT[BB * HH + b * HH + jj] = h1v;
    cT[BB * HH + b * HH + jj] = c1;
  }
}

// ---------------------------------------------------------------------------
extern "C" void kernel_launch(void* const* d_in, const int* in_sizes, int n_in,
                              void* d_out, int out_size, void* d_ws, size_t ws_size,
                              hipStream_t stream) {
  const float* x   = (const float*)d_in[0];
  const float* Wx0 = (const float*)d_in[1];
  const float* Wh0 = (const float*)d_in[2];
  const float* b0  = (const float*)d_in[3];
  const float* Wx1 = (const float*)d_in[4];
  const float* Wh1 = (const float*)d_in[5];
  const float* b1  = (const float*)d_in[6];
  float* out = (float*)d_out;

  // Workspace: Xg f16 [B][512][T] = 128 MB, then WT fp32 [128][512]
  __half* Xg = (__half*)d_ws;
  float* WT = (float*)((char*)d_ws + (size_t)BB * TT * NG * sizeof(__half));

  wx0_transpose<<<(NG * II + 255) / 256, 256, 0, stream>>>(Wx0, WT);
  xg0_gemm<<<dim3((BB * TT) / 64, NG / 64), 256, 0, stream>>>(x, WT, b0, Xg);
  lstm_rec<<<BB, 1024, 0, stream>>>(Xg, Wh0, Wx1, Wh1, b1, out);
}

// Round 5
// 2582.579 us; speedup vs baseline: 1.2359x; 1.2359x over previous
//
#include <hip/hip_runtime.h>
#include <hip/hip_fp16.h>

// Problem constants
#define BB 64
#define TT 2048
#define II 128
#define HH 128
#define NG 512  // 4*H

typedef _Float16 h2_t __attribute__((ext_vector_type(2)));

#if defined(__has_builtin)
#if __has_builtin(__builtin_amdgcn_fdot2)
#define HAVE_FDOT2 1
#endif
#endif

__device__ __forceinline__ float fdot2f(h2_t a, h2_t b, float c) {
#ifdef HAVE_FDOT2
  return __builtin_amdgcn_fdot2(a, b, c, false);
#else
  float d;
  asm("v_dot2_f32_f16 %0, %1, %2, %3" : "=v"(d) : "v"(a), "v"(b), "v"(c));
  return d;
#endif
}

__device__ __forceinline__ float fast_sigmoid(float x) {
  float t = __builtin_amdgcn_exp2f(-1.4426950408889634f * x);
  return __builtin_amdgcn_rcpf(1.0f + t);
}

// sigmoid(x) normally; tanh(x) = 2*sigmoid(2x)-1 for the g-gate rows.
__device__ __forceinline__ float act_gate(float x, bool tanh_sel) {
  float xx = tanh_sel ? 2.0f * x : x;
  float s = fast_sigmoid(xx);
  return tanh_sel ? 2.0f * s - 1.0f : s;
}

__device__ __forceinline__ float fast_tanh(float x) {
  return 2.0f * fast_sigmoid(2.0f * x) - 1.0f;
}

// Pair sum via DPP quad_perm:[1,0,3,2] — both lanes of the (even,odd) pair
// get the full sum. VALU-only: no LDS-pipe traffic (unlike __shfl_xor).
__device__ __forceinline__ float pairsum(float x) {
  int y = __builtin_amdgcn_update_dpp(0, __float_as_int(x), 0xB1, 0xF, 0xF, true);
  return x + __int_as_float(y);
}

// LDS-only barrier: does NOT drain vmcnt, so global prefetch/stores stay queued.
__device__ __forceinline__ void bar_lds() {
  asm volatile("s_waitcnt lgkmcnt(0)\n\ts_barrier" ::: "memory");
}

union F4H {
  float4 f4;
  h2_t h[4];
};

// ---------------------------------------------------------------------------
// Transpose Wx0 [512][128] -> WT [128][512] (fp32), tiny
// ---------------------------------------------------------------------------
__global__ void wx0_transpose(const float* __restrict__ W, float* __restrict__ WT) {
  int idx = blockIdx.x * 256 + threadIdx.x;
  if (idx < NG * II) {
    int n = idx >> 7;
    int k = idx & 127;
    WT[k * NG + n] = W[idx];
  }
}

// ---------------------------------------------------------------------------
// Xg = x @ Wx0^T + b0, stored f16 TRANSPOSED as [B][512][T] so the
// recurrence reads each gate stream contiguously along t.
// ---------------------------------------------------------------------------
__global__ __launch_bounds__(256) void xg0_gemm(const float* __restrict__ X,
                                                const float* __restrict__ WT,  // [128][512]
                                                const float* __restrict__ bias,
                                                __half* __restrict__ Xg) {   // [B][512][T]
  __shared__ float As[64][132];
  __shared__ float Bs[128][64];
  const int m0 = blockIdx.x * 64;
  const int n0 = blockIdx.y * 64;
  const int tid = threadIdx.x;

  {
    const float4* xv = (const float4*)(X + (size_t)m0 * II);
#pragma unroll
    for (int r = 0; r < 8; ++r) {
      int f = tid + 256 * r;
      int m = f >> 5;
      int c4 = f & 31;
      float4 v = xv[m * 32 + c4];
      *(float4*)&As[m][c4 * 4] = v;
    }
  }
  {
#pragma unroll
    for (int r = 0; r < 8; ++r) {
      int f = tid + 256 * r;
      int k = f >> 4;
      int q = f & 15;
      float4 v = *(const float4*)(WT + (size_t)k * NG + n0 + q * 4);
      *(float4*)&Bs[k][q * 4] = v;
    }
  }
  __syncthreads();

  const int tx = tid & 15;
  const int ty = tid >> 4;
  float acc[4][4];
#pragma unroll
  for (int i = 0; i < 4; ++i)
#pragma unroll
    for (int j = 0; j < 4; ++j) acc[i][j] = 0.0f;

#pragma unroll 4
  for (int k = 0; k < 128; ++k) {
    float a0 = As[ty * 4 + 0][k];
    float a1 = As[ty * 4 + 1][k];
    float a2 = As[ty * 4 + 2][k];
    float a3 = As[ty * 4 + 3][k];
    float4 bv = *(const float4*)&Bs[k][tx * 4];
    acc[0][0] = fmaf(a0, bv.x, acc[0][0]);
    acc[0][1] = fmaf(a0, bv.y, acc[0][1]);
    acc[0][2] = fmaf(a0, bv.z, acc[0][2]);
    acc[0][3] = fmaf(a0, bv.w, acc[0][3]);
    acc[1][0] = fmaf(a1, bv.x, acc[1][0]);
    acc[1][1] = fmaf(a1, bv.y, acc[1][1]);
    acc[1][2] = fmaf(a1, bv.z, acc[1][2]);
    acc[1][3] = fmaf(a1, bv.w, acc[1][3]);
    acc[2][0] = fmaf(a2, bv.x, acc[2][0]);
    acc[2][1] = fmaf(a2, bv.y, acc[2][1]);
    acc[2][2] = fmaf(a2, bv.z, acc[2][2]);
    acc[2][3] = fmaf(a2, bv.w, acc[2][3]);
    acc[3][0] = fmaf(a3, bv.x, acc[3][0]);
    acc[3][1] = fmaf(a3, bv.y, acc[3][1]);
    acc[3][2] = fmaf(a3, bv.z, acc[3][2]);
    acc[3][3] = fmaf(a3, bv.w, acc[3][3]);
  }

  float4 bvec = *(const float4*)(bias + n0 + tx * 4);
  float bb[4] = {bvec.x, bvec.y, bvec.z, bvec.w};
  const int b = m0 >> 11;        // 2048 % 64 == 0, tile never straddles b
  const int t0 = m0 & 2047;
  __half* base = Xg + (size_t)b * NG * TT + (size_t)t0 + (size_t)(ty * 4);
#pragma unroll
  for (int j = 0; j < 4; ++j) {
    int nn = n0 + tx * 4 + j;
    union { __half2 h[2]; uint2 u; } pk;
    pk.h[0] = __halves2half2(__float2half(acc[0][j] + bb[j]),
                             __float2half(acc[1][j] + bb[j]));
    pk.h[1] = __halves2half2(__float2half(acc[2][j] + bb[j]),
                             __float2half(acc[3][j] + bb[j]));
    *(uint2*)(base + (size_t)nn * TT) = pk.u;
  }
}

// ---------------------------------------------------------------------------
// Recurrence: one WG per batch element, 512 threads (8 waves -> 2 waves/EU,
// 256-reg budget). Thread n = 2q+p owns K-half p of gate rows q AND q+256
// for all three matrices (192 f16x2 weight regs) -> halves the LDS read
// count per CU vs the 1024-thread version (h tile reused for 2 rows).
// Pair partials combined with DPP quad_perm (VALU, no LDS). Lane p writes
// gate row q+(p<<8). Layer-skewed: iter i computes g0(i) and g1(i-1),
// 2 LDS-only barriers per step.
// ---------------------------------------------------------------------------
__global__
__attribute__((amdgpu_flat_work_group_size(512, 512)))
__attribute__((amdgpu_waves_per_eu(2, 2)))
void lstm_rec(
    const __half* __restrict__ Xg,    // [B][512][T], includes b0
    const float* __restrict__ Wh0,    // [512][128]
    const float* __restrict__ Wx1,    // [512][128]
    const float* __restrict__ Wh1,    // [512][128]
    const float* __restrict__ b1,     // [512]
    float* __restrict__ out)          // output | hT | cT
{
  const int b = blockIdx.x;
  const int n = threadIdx.x;
  const int q = n >> 1;
  const int p = n & 1;
  const int rA = q;
  const int rB = q + 256;
  const int row = q + (p << 8);          // the gate row this lane WRITES
  const bool tsel = ((row >> 7) == 2);   // g-gate rows 256..383 -> tanh

  // Per-thread K-half weight rows for rA and rB, f32 -> f16x2 registers
  h2_t whA[32], whB[32], wxA[32], wxB[32], wvA[32], wvB[32];
  {
    const float2* a0p = (const float2*)(Wh0 + (size_t)rA * HH + p * 64);
    const float2* b0p = (const float2*)(Wh0 + (size_t)rB * HH + p * 64);
    const float2* a1p = (const float2*)(Wx1 + (size_t)rA * HH + p * 64);
    const float2* b1p = (const float2*)(Wx1 + (size_t)rB * HH + p * 64);
    const float2* a2p = (const float2*)(Wh1 + (size_t)rA * HH + p * 64);
    const float2* b2p = (const float2*)(Wh1 + (size_t)rB * HH + p * 64);
#pragma unroll
    for (int k = 0; k < 32; ++k) {
      float2 v;
      v = a0p[k]; whA[k][0] = (_Float16)v.x; whA[k][1] = (_Float16)v.y;
      v = b0p[k]; whB[k][0] = (_Float16)v.x; whB[k][1] = (_Float16)v.y;
      v = a1p[k]; wxA[k][0] = (_Float16)v.x; wxA[k][1] = (_Float16)v.y;
      v = b1p[k]; wxB[k][0] = (_Float16)v.x; wxB[k][1] = (_Float16)v.y;
      v = a2p[k]; wvA[k][0] = (_Float16)v.x; wvA[k][1] = (_Float16)v.y;
      v = b2p[k]; wvB[k][0] = (_Float16)v.x; wvB[k][1] = (_Float16)v.y;
    }
  }
  const float bias1 = b1[row];

  __shared__ __align__(16) h2_t h0p[64];   // h0(t-1) as f16
  __shared__ __align__(16) h2_t h1p[64];   // h1(t-2) as f16
  __shared__ float gbuf[1024];             // [0..511]=g0 act, [512..1023]=g1 act

  if (n < 64) {
    h2_t z;
    z[0] = (_Float16)0.0f;
    z[1] = (_Float16)0.0f;
    h0p[n] = z;
    h1p[n] = z;
  }
  float c0 = 0.0f, c1 = 0.0f;
  float h0v = 0.0f, h1v = 0.0f;
  __syncthreads();

  const uint4* xs = (const uint4*)(Xg + ((size_t)b * NG + row) * TT);
  float* outp = out + (size_t)b * TT * HH;
  float* hT = out + (size_t)BB * TT * HH;   // [2][64][128]
  float* cT = hT + 2 * BB * HH;

  const float4* H0 = (const float4*)((const char*)h0p + (p << 7));
  const float4* H1 = (const float4*)((const char*)h1p + (p << 7));

  uint4 xcur = xs[0];

  for (int tc = 0; tc < TT / 8; ++tc) {
    uint4 xnext = xs[(tc + 1) & (TT / 8 - 1)];  // stays in flight across barriers
#pragma unroll
    for (int s = 0; s < 8; ++s) {
      const int i = tc * 8 + s;
      const float xg = (float)((const _Float16*)&xcur)[s];

      // ---- Phase 1: 192 dot2 -> rows rA,rB of g0(i) and g1(i-1) ----
      float a0 = 0.f, a1 = 0.f, bb0 = 0.f, bb1 = 0.f;
      float xa0 = 0.f, xa1 = 0.f, xb0 = 0.f, xb1 = 0.f;
#pragma unroll
      for (int qi = 0; qi < 8; ++qi) {
        F4H u0; u0.f4 = H0[qi];
        F4H u1; u1.f4 = H1[qi];
        a0  = fdot2f(whA[4 * qi + 0], u0.h[0], a0);
        a1  = fdot2f(whA[4 * qi + 1], u0.h[1], a1);
        a0  = fdot2f(whA[4 * qi + 2], u0.h[2], a0);
        a1  = fdot2f(whA[4 * qi + 3], u0.h[3], a1);
        bb0 = fdot2f(whB[4 * qi + 0], u0.h[0], bb0);
        bb1 = fdot2f(whB[4 * qi + 1], u0.h[1], bb1);
        bb0 = fdot2f(whB[4 * qi + 2], u0.h[2], bb0);
        bb1 = fdot2f(whB[4 * qi + 3], u0.h[3], bb1);
        xa0 = fdot2f(wxA[4 * qi + 0], u0.h[0], xa0);
        xa1 = fdot2f(wxA[4 * qi + 1], u0.h[1], xa1);
        xa0 = fdot2f(wxA[4 * qi + 2], u0.h[2], xa0);
        xa1 = fdot2f(wxA[4 * qi + 3], u0.h[3], xa1);
        xb0 = fdot2f(wxB[4 * qi + 0], u0.h[0], xb0);
        xb1 = fdot2f(wxB[4 * qi + 1], u0.h[1], xb1);
        xb0 = fdot2f(wxB[4 * qi + 2], u0.h[2], xb0);
        xb1 = fdot2f(wxB[4 * qi + 3], u0.h[3], xb1);
        xa0 = fdot2f(wvA[4 * qi + 0], u1.h[0], xa0);
        xa1 = fdot2f(wvA[4 * qi + 1], u1.h[1], xa1);
        xa0 = fdot2f(wvA[4 * qi + 2], u1.h[2], xa0);
        xa1 = fdot2f(wvA[4 * qi + 3], u1.h[3], xa1);
        xb0 = fdot2f(wvB[4 * qi + 0], u1.h[0], xb0);
        xb1 = fdot2f(wvB[4 * qi + 1], u1.h[1], xb1);
        xb0 = fdot2f(wvB[4 * qi + 2], u1.h[2], xb0);
        xb1 = fdot2f(wvB[4 * qi + 3], u1.h[3], xb1);
      }
      const float sA0 = pairsum(a0 + a1);    // Wh0[rA].h0
      const float sB0 = pairsum(bb0 + bb1);  // Wh0[rB].h0
      const float sA1 = pairsum(xa0 + xa1);  // Wx1[rA].h0 + Wh1[rA].h1
      const float sB1 = pairsum(xb0 + xb1);  // Wx1[rB].h0 + Wh1[rB].h1
      const float v0 = (p ? sB0 : sA0) + xg;
      const float v1 = (p ? sB1 : sA1) + bias1;
      gbuf[row] = act_gate(v0, tsel);
      gbuf[512 + row] = act_gate(v1, tsel);
      bar_lds();

      // ---- Phase 2: cell updates (wave 0: L0 step i; wave 1: L1 step i-1) ----
      if (n < 128) {
        float gi = gbuf[n], gf = gbuf[n + 128], gg = gbuf[n + 256], go = gbuf[n + 384];
        c0 = gf * c0 + gi * gg;
        h0v = go * fast_tanh(c0);
        ((_Float16*)h0p)[n] = (_Float16)h0v;
      } else if (n < 256) {
        if (i > 0) {
          int jj = n - 128;
          float gi = gbuf[jj + 512], gf = gbuf[jj + 640], gg = gbuf[jj + 768], go = gbuf[jj + 896];
          c1 = gf * c1 + gi * gg;
          h1v = go * fast_tanh(c1);
          ((_Float16*)h1p)[jj] = (_Float16)h1v;
          outp[(size_t)(i - 1) * HH + jj] = h1v;
        }
      }
      bar_lds();
    }
    xcur = xnext;
  }

  // ---- Epilogue: g1 for step TT-1 (needs h0(TT-1), h1(TT-2)) ----
  {
    float xa0 = 0.f, xa1 = 0.f, xb0 = 0.f, xb1 = 0.f;
#pragma unroll
    for (int qi = 0; qi < 8; ++qi) {
      F4H u0; u0.f4 = H0[qi];
      F4H u1; u1.f4 = H1[qi];
      xa0 = fdot2f(wxA[4 * qi + 0], u0.h[0], xa0);
      xa1 = fdot2f(wxA[4 * qi + 1], u0.h[1], xa1);
      xa0 = fdot2f(wxA[4 * qi + 2], u0.h[2], xa0);
      xa1 = fdot2f(wxA[4 * qi + 3], u0.h[3], xa1);
      xb0 = fdot2f(wxB[4 * qi + 0], u0.h[0], xb0);
      xb1 = fdot2f(wxB[4 * qi + 1], u0.h[1], xb1);
      xb0 = fdot2f(wxB[4 * qi + 2], u0.h[2], xb0);
      xb1 = fdot2f(wxB[4 * qi + 3], u0.h[3], xb1);
      xa0 = fdot2f(wvA[4 * qi + 0], u1.h[0], xa0);
      xa1 = fdot2f(wvA[4 * qi + 1], u1.h[1], xa1);
      xa0 = fdot2f(wvA[4 * qi + 2], u1.h[2], xa0);
      xa1 = fdot2f(wvA[4 * qi + 3], u1.h[3], xa1);
      xb0 = fdot2f(wvB[4 * qi + 0], u1.h[0], xb0);
      xb1 = fdot2f(wvB[4 * qi + 1], u1.h[1], xb1);
      xb0 = fdot2f(wvB[4 * qi + 2], u1.h[2], xb0);
      xb1 = fdot2f(wvB[4 * qi + 3], u1.h[3], xb1);
    }
    const float sA1 = pairsum(xa0 + xa1);
    const float sB1 = pairsum(xb0 + xb1);
    gbuf[512 + row] = act_gate((p ? sB1 : sA1) + bias1, tsel);
    bar_lds();
    if (n >= 128 && n < 256) {
      int jj = n - 128;
      float gi = gbuf[jj + 512], gf = gbuf[jj + 640], gg = gbuf[jj + 768], go = gbuf[jj + 896];
      c1 = gf * c1 + gi * gg;
      h1v = go * fast_tanh(c1);
      outp[(size_t)(TT - 1) * HH + jj] = h1v;
    }
  }

  // ---- Final states ----
  if (n < 128) {
    hT[b * HH + n] = h0v;
    cT[b * HH + n] = c0;
  } else if (n < 256) {
    int jj = n - 128;
    hT[BB * HH + b * HH + jj] = h1v;
    cT[BB * HH + b * HH + jj] = c1;
  }
}

// ---------------------------------------------------------------------------
extern "C" void kernel_launch(void* const* d_in, const int* in_sizes, int n_in,
                              void* d_out, int out_size, void* d_ws, size_t ws_size,
                              hipStream_t stream) {
  const float* x   = (const float*)d_in[0];
  const float* Wx0 = (const float*)d_in[1];
  const float* Wh0 = (const float*)d_in[2];
  const float* b0  = (const float*)d_in[3];
  const float* Wx1 = (const float*)d_in[4];
  const float* Wh1 = (const float*)d_in[5];
  const float* b1  = (const float*)d_in[6];
  float* out = (float*)d_out;

  // Workspace: Xg f16 [B][512][T] = 128 MB, then WT fp32 [128][512]
  __half* Xg = (__half*)d_ws;
  float* WT = (float*)((char*)d_ws + (size_t)BB * TT * NG * sizeof(__half));

  wx0_transpose<<<(NG * II + 255) / 256, 256, 0, stream>>>(Wx0, WT);
  xg0_gemm<<<dim3((BB * TT) / 64, NG / 64), 256, 0, stream>>>(x, WT, b0, Xg);
  lstm_rec<<<BB, 512, 0, stream>>>(Xg, Wh0, Wx1, Wh1, b1, out);
}